// Round 1
// baseline (154.812 us; speedup 1.0000x reference)
//
#include <hip/hip_runtime.h>
#include <math.h>

#define N_ROWS 65536
#define M_DIM  512
#define H_DIM  1024
#define EPS    1e-8f

// ---- workspace layout (in floats) ----
#define WS_GATES 0          // 4096
#define WS_KVEC  4096       // 512
#define WS_KN    4608       // 512
#define WS_ERASE 5120       // 512
#define WS_ADD   5632       // 512
#define WS_SCAL  6144       // [0]=beta_raw, [1]=beta
#define WS_SIM   8192       // 65536
#define WS_W     73728      // 65536
#define WS_PART  139264     // NBLK_B * 512
#define NBLK_B   1024

__device__ __forceinline__ float sigmoidf_(float v) { return 1.f / (1.f + expf(-v)); }

// ---- gates = W_ih@xi + b_ih + W_hh@h0 + b_hh ; one wave per row (4096 rows) ----
__global__ void k_gates(const float* __restrict__ x, const float* __restrict__ rv,
                        const float* __restrict__ h0,
                        const float* __restrict__ W_ih, const float* __restrict__ b_ih,
                        const float* __restrict__ W_hh, const float* __restrict__ b_hh,
                        float* __restrict__ gates) {
    int wave = (blockIdx.x * blockDim.x + threadIdx.x) >> 6;
    int lane = threadIdx.x & 63;
    if (wave >= 4 * H_DIM) return;
    const float4* Wi = (const float4*)(W_ih + (size_t)wave * 1024);
    const float4* Wh = (const float4*)(W_hh + (size_t)wave * 1024);
    const float4* xv = (const float4*)x;
    const float4* rvv = (const float4*)rv;
    const float4* hv = (const float4*)h0;
    float s = 0.f;
#pragma unroll
    for (int k = 0; k < 4; ++k) {
        int idx = k * 64 + lane;                 // 0..255 float4s
        float4 wiv = Wi[idx];
        float4 in4 = (k < 2) ? xv[idx] : rvv[idx - 128];
        s += wiv.x * in4.x + wiv.y * in4.y + wiv.z * in4.z + wiv.w * in4.w;
        float4 whv = Wh[idx];
        float4 h4 = hv[idx];
        s += whv.x * h4.x + whv.y * h4.y + whv.z * h4.z + whv.w * h4.w;
    }
#pragma unroll
    for (int o = 32; o > 0; o >>= 1) s += __shfl_xor(s, o);
    if (lane == 0) gates[wave] = s + b_ih[wave] + b_hh[wave];
}

// ---- LSTM cell elementwise; 1 block x 1024 threads ----
__global__ void k_cell(const float* __restrict__ gates, const float* __restrict__ c0,
                       float* __restrict__ h_out, float* __restrict__ c_out) {
    int j = threadIdx.x;
    float ig = sigmoidf_(gates[j]);
    float fg = sigmoidf_(gates[j + 1024]);
    float gg = tanhf(gates[j + 2048]);
    float og = sigmoidf_(gates[j + 3072]);
    float c = fg * c0[j] + ig * gg;
    float h = og * tanhf(c);
    c_out[j] = c;
    h_out[j] = h;
}

// ---- 5 head matvecs vs h; one wave per output row (2049 rows) ----
__global__ void k_heads(const float* __restrict__ h,
                        const float* __restrict__ W_fc, const float* __restrict__ b_fc,
                        const float* __restrict__ W_key, const float* __restrict__ b_key,
                        const float* __restrict__ W_beta, const float* __restrict__ b_beta,
                        const float* __restrict__ W_erase, const float* __restrict__ b_erase,
                        const float* __restrict__ W_add, const float* __restrict__ b_add,
                        float* __restrict__ out, float* __restrict__ kvec,
                        float* __restrict__ scal, float* __restrict__ erase,
                        float* __restrict__ addv) {
    int wave = (blockIdx.x * blockDim.x + threadIdx.x) >> 6;
    int lane = threadIdx.x & 63;
    if (wave >= 2049) return;
    const float* Wrow;
    float bias;
    int kind, r;
    if (wave < 512)        { kind = 0; r = wave;        Wrow = W_fc    + (size_t)r * 1024; bias = b_fc[r]; }
    else if (wave < 1024)  { kind = 1; r = wave - 512;  Wrow = W_key   + (size_t)r * 1024; bias = b_key[r]; }
    else if (wave == 1024) { kind = 2; r = 0;           Wrow = W_beta;                     bias = b_beta[0]; }
    else if (wave < 1537)  { kind = 3; r = wave - 1025; Wrow = W_erase + (size_t)r * 1024; bias = b_erase[r]; }
    else                   { kind = 4; r = wave - 1537; Wrow = W_add   + (size_t)r * 1024; bias = b_add[r]; }
    const float4* Wv = (const float4*)Wrow;
    const float4* hv = (const float4*)h;
    float s = 0.f;
#pragma unroll
    for (int k = 0; k < 4; ++k) {
        int idx = k * 64 + lane;
        float4 w4 = Wv[idx];
        float4 h4 = hv[idx];
        s += w4.x * h4.x + w4.y * h4.y + w4.z * h4.z + w4.w * h4.w;
    }
#pragma unroll
    for (int o = 32; o > 0; o >>= 1) s += __shfl_xor(s, o);
    if (lane == 0) {
        float v = s + bias;
        if (kind == 0)      out[r]   = sigmoidf_(v);
        else if (kind == 1) kvec[r]  = tanhf(v);
        else if (kind == 2) scal[0]  = v;               // raw beta
        else if (kind == 3) erase[r] = sigmoidf_(v);
        else                addv[r]  = tanhf(v);
    }
}

// ---- kn = kvec/(||kvec||+eps); beta = softplus(raw)+eps ; 1 block x 512 ----
__global__ void k_norm(const float* __restrict__ kvec, float* __restrict__ kn,
                       float* __restrict__ scal) {
    __shared__ float red[512];
    __shared__ float invn;
    int t = threadIdx.x;
    float v = kvec[t];
    red[t] = v * v;
    __syncthreads();
#pragma unroll
    for (int s = 256; s > 0; s >>= 1) {
        if (t < s) red[t] += red[t + s];
        __syncthreads();
    }
    if (t == 0) {
        invn = 1.f / (sqrtf(red[0]) + EPS);
        float braw = scal[0];
        float sp = (braw > 20.f) ? braw : log1pf(expf(braw));
        scal[1] = sp + EPS;
    }
    __syncthreads();
    kn[t] = v * invn;
}

// ---- sim[n] = dot(mem[n], kn) / (||mem[n]||+eps); one wave per row, grid-stride ----
__global__ void __launch_bounds__(256) k_sim(const float* __restrict__ mem,
                                             const float* __restrict__ kn,
                                             float* __restrict__ sim) {
    int gw = (blockIdx.x * blockDim.x + threadIdx.x) >> 6;
    int lane = threadIdx.x & 63;
    int nw = (gridDim.x * blockDim.x) >> 6;
    float4 k0 = ((const float4*)kn)[lane];
    float4 k1 = ((const float4*)kn)[64 + lane];
    for (int row = gw; row < N_ROWS; row += nw) {
        const float4* mv = (const float4*)(mem + (size_t)row * M_DIM);
        float4 m0 = mv[lane];
        float4 m1 = mv[64 + lane];
        float dot = m0.x * k0.x + m0.y * k0.y + m0.z * k0.z + m0.w * k0.w
                  + m1.x * k1.x + m1.y * k1.y + m1.z * k1.z + m1.w * k1.w;
        float ss  = m0.x * m0.x + m0.y * m0.y + m0.z * m0.z + m0.w * m0.w
                  + m1.x * m1.x + m1.y * m1.y + m1.z * m1.z + m1.w * m1.w;
#pragma unroll
        for (int o = 32; o > 0; o >>= 1) {
            dot += __shfl_xor(dot, o);
            ss  += __shfl_xor(ss, o);
        }
        if (lane == 0) sim[row] = dot / (sqrtf(ss) + EPS);
    }
}

// ---- w = softmax(beta*sim); 1 block x 1024 ----
__global__ void k_softmax(const float* __restrict__ sim, const float* __restrict__ scal,
                          float* __restrict__ w) {
    __shared__ float red[1024];
    int t = threadIdx.x;
    float beta = scal[1];
    float mx = -1e30f;
    for (int i = t; i < N_ROWS; i += 1024) mx = fmaxf(mx, beta * sim[i]);
    red[t] = mx;
    __syncthreads();
#pragma unroll
    for (int s = 512; s > 0; s >>= 1) {
        if (t < s) red[t] = fmaxf(red[t], red[t + s]);
        __syncthreads();
    }
    float m = red[0];
    __syncthreads();
    float sum = 0.f;
    for (int i = t; i < N_ROWS; i += 1024) sum += expf(beta * sim[i] - m);
    red[t] = sum;
    __syncthreads();
#pragma unroll
    for (int s = 512; s > 0; s >>= 1) {
        if (t < s) red[t] += red[t + s];
        __syncthreads();
    }
    float inv = 1.f / red[0];
    for (int i = t; i < N_ROWS; i += 1024) w[i] = expf(beta * sim[i] - m) * inv;
}

// ---- mem_new + partial read_new; 1024 blocks x 256, 64 rows/block ----
__global__ void __launch_bounds__(256) k_update(const float* __restrict__ mem,
                                                const float* __restrict__ w,
                                                const float* __restrict__ erase,
                                                const float* __restrict__ addv,
                                                float* __restrict__ mem_out,
                                                float* __restrict__ partial) {
    __shared__ float4 s_e[128];
    __shared__ float4 s_a[128];
    __shared__ float  s_w[64];
    __shared__ float4 s_red[128];
    int t = threadIdx.x;
    if (t < 128) {
        s_e[t] = ((const float4*)erase)[t];
        s_a[t] = ((const float4*)addv)[t];
    }
    int rowBase = blockIdx.x * 64;
    if (t < 64) s_w[t] = w[rowBase + t];
    __syncthreads();
    int sub = t >> 7;     // 0 or 1: which of the 2 rows per iteration
    int c4  = t & 127;    // float4 column index
    float4 e4 = s_e[c4];
    float4 a4 = s_a[c4];
    float4 acc = make_float4(0.f, 0.f, 0.f, 0.f);
#pragma unroll 4
    for (int it = 0; it < 32; ++it) {
        int row = rowBase + it * 2 + sub;
        float wr = s_w[it * 2 + sub];
        float4 m4 = ((const float4*)(mem + (size_t)row * M_DIM))[c4];
        float4 n4;
        n4.x = m4.x * (1.f - wr * e4.x) + wr * a4.x;
        n4.y = m4.y * (1.f - wr * e4.y) + wr * a4.y;
        n4.z = m4.z * (1.f - wr * e4.z) + wr * a4.z;
        n4.w = m4.w * (1.f - wr * e4.w) + wr * a4.w;
        ((float4*)(mem_out + (size_t)row * M_DIM))[c4] = n4;
        acc.x += wr * n4.x;
        acc.y += wr * n4.y;
        acc.z += wr * n4.z;
        acc.w += wr * n4.w;
    }
    if (sub) s_red[c4] = acc;
    __syncthreads();
    if (!sub) {
        float4 o = s_red[c4];
        acc.x += o.x; acc.y += o.y; acc.z += o.z; acc.w += o.w;
        ((float4*)(partial + (size_t)blockIdx.x * M_DIM))[c4] = acc;
    }
}

// ---- read_new[m] = sum_b partial[b][m]; 2 blocks x 256 ----
__global__ void k_reduce(const float* __restrict__ partial, float* __restrict__ read_new) {
    int m = blockIdx.x * blockDim.x + threadIdx.x;
    float s0 = 0.f, s1 = 0.f, s2 = 0.f, s3 = 0.f;
    for (int b = 0; b < NBLK_B; b += 4) {
        s0 += partial[(size_t)b * M_DIM + m];
        s1 += partial[(size_t)(b + 1) * M_DIM + m];
        s2 += partial[(size_t)(b + 2) * M_DIM + m];
        s3 += partial[(size_t)(b + 3) * M_DIM + m];
    }
    read_new[m] = (s0 + s1) + (s2 + s3);
}

extern "C" void kernel_launch(void* const* d_in, const int* in_sizes, int n_in,
                              void* d_out, int out_size, void* d_ws, size_t ws_size,
                              hipStream_t stream) {
    const float* x        = (const float*)d_in[0];
    const float* h0       = (const float*)d_in[1];
    const float* c0       = (const float*)d_in[2];
    const float* memory   = (const float*)d_in[3];
    const float* read_vec = (const float*)d_in[4];
    const float* W_ih     = (const float*)d_in[5];
    const float* b_ih     = (const float*)d_in[6];
    const float* W_hh     = (const float*)d_in[7];
    const float* b_hh     = (const float*)d_in[8];
    const float* W_fc     = (const float*)d_in[9];
    const float* b_fc     = (const float*)d_in[10];
    const float* W_key    = (const float*)d_in[11];
    const float* b_key    = (const float*)d_in[12];
    const float* W_beta   = (const float*)d_in[13];
    const float* b_beta   = (const float*)d_in[14];
    const float* W_erase  = (const float*)d_in[15];
    const float* b_erase  = (const float*)d_in[16];
    const float* W_add    = (const float*)d_in[17];
    const float* b_add    = (const float*)d_in[18];

    float* out      = (float*)d_out;                       // 512
    float* h_out    = out + 512;                           // 1024
    float* c_out    = h_out + 1024;                        // 1024
    float* mem_out  = c_out + 1024;                        // N*M
    float* read_out = mem_out + (size_t)N_ROWS * M_DIM;    // 512

    float* ws     = (float*)d_ws;
    float* gates  = ws + WS_GATES;
    float* kvec   = ws + WS_KVEC;
    float* kn     = ws + WS_KN;
    float* erase  = ws + WS_ERASE;
    float* addv   = ws + WS_ADD;
    float* scal   = ws + WS_SCAL;
    float* sim    = ws + WS_SIM;
    float* wv     = ws + WS_W;
    float* part   = ws + WS_PART;

    // gates: 4096 waves -> 1024 blocks x 256
    k_gates<<<1024, 256, 0, stream>>>(x, read_vec, h0, W_ih, b_ih, W_hh, b_hh, gates);
    // cell
    k_cell<<<1, 1024, 0, stream>>>(gates, c0, h_out, c_out);
    // heads: 2049 waves -> 513 blocks x 256
    k_heads<<<513, 256, 0, stream>>>(h_out, W_fc, b_fc, W_key, b_key, W_beta, b_beta,
                                     W_erase, b_erase, W_add, b_add,
                                     out, kvec, scal, erase, addv);
    // key normalize + beta softplus
    k_norm<<<1, 512, 0, stream>>>(kvec, kn, scal);
    // similarity over memory (128 MB read)
    k_sim<<<2048, 256, 0, stream>>>(memory, kn, sim);
    // softmax over N
    k_softmax<<<1, 1024, 0, stream>>>(sim, scal, wv);
    // memory update + read partials (128 MB read + 128 MB write)
    k_update<<<NBLK_B, 256, 0, stream>>>(memory, wv, erase, addv, mem_out, part);
    // final read_new reduction
    k_reduce<<<2, 256, 0, stream>>>(part, read_out);
}

// Round 3
// 99.893 us; speedup vs baseline: 1.5498x; 1.5498x over previous
//
#include <hip/hip_runtime.h>
#include <math.h>

#define N_ROWS 65536
#define M_DIM  512
#define H_DIM  1024
#define EPS    1e-8f
#define NBLK_U 2048   // k_update blocks (32 rows each)
#define NBLK_S 2048   // k_simexp blocks (32 rows each)

__device__ __forceinline__ float sigmoidf_(float v) { return 1.f / (1.f + expf(-v)); }

// ---- workspace layout (floats) ----
#define WS_KVEC  0          // 512
#define WS_ERASE 512        // 512
#define WS_ADD   1024       // 512
#define WS_SCAL  1536       // [0]=beta_raw
#define WS_P     2048       // 65536 unnormalized exp(beta*sim)
#define WS_PSUM  67584      // 2048 per-simexp-block sums
#define WS_PART  69632      // 2048*512 per-update-block read partials
#define WS_OUT1  1118208    // 64*512 stage-1 reduced partials

// ---- fused gates matvec + LSTM cell: 1024 blocks x 256 (4 waves = gates i,f,g,o of one j) ----
__global__ void __launch_bounds__(256) k_gatecell(
        const float* __restrict__ x, const float* __restrict__ rv,
        const float* __restrict__ h0, const float* __restrict__ c0,
        const float* __restrict__ W_ih, const float* __restrict__ b_ih,
        const float* __restrict__ W_hh, const float* __restrict__ b_hh,
        float* __restrict__ h_out, float* __restrict__ c_out) {
    __shared__ float gval[4];
    int j = blockIdx.x;                 // hidden index 0..1023
    int wid = threadIdx.x >> 6;         // gate kind 0..3 (i,f,g,o)
    int lane = threadIdx.x & 63;
    int r = wid * H_DIM + j;            // gate row in [0,4096)
    const float4* Wi = (const float4*)(W_ih + (size_t)r * 1024);
    const float4* Wh = (const float4*)(W_hh + (size_t)r * 1024);
    const float4* xv = (const float4*)x;
    const float4* rvv = (const float4*)rv;
    const float4* hv = (const float4*)h0;
    float s = 0.f;
#pragma unroll
    for (int k = 0; k < 4; ++k) {
        int idx = k * 64 + lane;            // 0..255 float4s
        float4 wiv = Wi[idx];
        float4 in4 = (k < 2) ? xv[idx] : rvv[idx - 128];
        s += wiv.x * in4.x + wiv.y * in4.y + wiv.z * in4.z + wiv.w * in4.w;
        float4 whv = Wh[idx];
        float4 h4 = hv[idx];
        s += whv.x * h4.x + whv.y * h4.y + whv.z * h4.z + whv.w * h4.w;
    }
#pragma unroll
    for (int o = 32; o > 0; o >>= 1) s += __shfl_xor(s, o);
    if (lane == 0) gval[wid] = s + b_ih[r] + b_hh[r];
    __syncthreads();
    if (threadIdx.x == 0) {
        float ig = sigmoidf_(gval[0]);
        float fg = sigmoidf_(gval[1]);
        float gg = tanhf(gval[2]);
        float og = sigmoidf_(gval[3]);
        float c = fg * c0[j] + ig * gg;
        float h = og * tanhf(c);
        c_out[j] = c;
        h_out[j] = h;
    }
}

// ---- 5 head matvecs vs h; one wave per output row (2049 rows) ----
__global__ void __launch_bounds__(256) k_heads(
        const float* __restrict__ h,
        const float* __restrict__ W_fc, const float* __restrict__ b_fc,
        const float* __restrict__ W_key, const float* __restrict__ b_key,
        const float* __restrict__ W_beta, const float* __restrict__ b_beta,
        const float* __restrict__ W_erase, const float* __restrict__ b_erase,
        const float* __restrict__ W_add, const float* __restrict__ b_add,
        float* __restrict__ out, float* __restrict__ kvec,
        float* __restrict__ scal, float* __restrict__ erase,
        float* __restrict__ addv) {
    int wave = (blockIdx.x * blockDim.x + threadIdx.x) >> 6;
    int lane = threadIdx.x & 63;
    if (wave >= 2049) return;
    const float* Wrow;
    float bias;
    int kind, r;
    if (wave < 512)        { kind = 0; r = wave;        Wrow = W_fc    + (size_t)r * 1024; bias = b_fc[r]; }
    else if (wave < 1024)  { kind = 1; r = wave - 512;  Wrow = W_key   + (size_t)r * 1024; bias = b_key[r]; }
    else if (wave == 1024) { kind = 2; r = 0;           Wrow = W_beta;                     bias = b_beta[0]; }
    else if (wave < 1537)  { kind = 3; r = wave - 1025; Wrow = W_erase + (size_t)r * 1024; bias = b_erase[r]; }
    else                   { kind = 4; r = wave - 1537; Wrow = W_add   + (size_t)r * 1024; bias = b_add[r]; }
    const float4* Wv = (const float4*)Wrow;
    const float4* hv = (const float4*)h;
    float s = 0.f;
#pragma unroll
    for (int k = 0; k < 4; ++k) {
        int idx = k * 64 + lane;
        float4 w4 = Wv[idx];
        float4 h4 = hv[idx];
        s += w4.x * h4.x + w4.y * h4.y + w4.z * h4.z + w4.w * h4.w;
    }
#pragma unroll
    for (int o = 32; o > 0; o >>= 1) s += __shfl_xor(s, o);
    if (lane == 0) {
        float v = s + bias;
        if (kind == 0)      out[r]   = sigmoidf_(v);
        else if (kind == 1) kvec[r]  = tanhf(v);
        else if (kind == 2) scal[0]  = v;               // raw beta
        else if (kind == 3) erase[r] = sigmoidf_(v);
        else                addv[r]  = tanhf(v);
    }
}

// ---- sim + exp fused: p[n] = exp(beta * cos(mem[n], k)); per-block partial sums ----
// each block redundantly computes ||kvec|| and beta (deterministic, L2-hit)
__global__ void __launch_bounds__(256) k_simexp(
        const float* __restrict__ mem, const float* __restrict__ kvec,
        const float* __restrict__ scal,
        float* __restrict__ p, float* __restrict__ psum) {
    __shared__ float red[256];
    __shared__ float skn[512];
    __shared__ float wsum[4];
    int t = threadIdx.x;
    float v0 = kvec[t];
    float v1 = kvec[t + 256];
    red[t] = v0 * v0 + v1 * v1;
    __syncthreads();
#pragma unroll
    for (int s2 = 128; s2 > 0; s2 >>= 1) {
        if (t < s2) red[t] += red[t + s2];
        __syncthreads();
    }
    float invn = 1.f / (sqrtf(red[0]) + EPS);
    float braw = scal[0];
    float beta = ((braw > 20.f) ? braw : log1pf(expf(braw))) + EPS;
    skn[t] = v0 * invn;
    skn[t + 256] = v1 * invn;
    __syncthreads();
    int wid = t >> 6, lane = t & 63;
    float4 k0 = ((const float4*)skn)[lane];
    float4 k1 = ((const float4*)skn)[64 + lane];
    int gw = blockIdx.x * 4 + wid;          // 0..8191
    size_t base = (size_t)gw * 8;           // 8 consecutive rows per wave
    float lsum = 0.f;
#pragma unroll 2
    for (int i = 0; i < 8; ++i) {
        size_t row = base + i;
        const float4* mv = (const float4*)(mem + row * M_DIM);
        float4 m0 = mv[lane];
        float4 m1 = mv[64 + lane];
        float dot = m0.x * k0.x + m0.y * k0.y + m0.z * k0.z + m0.w * k0.w
                  + m1.x * k1.x + m1.y * k1.y + m1.z * k1.z + m1.w * k1.w;
        float ss  = m0.x * m0.x + m0.y * m0.y + m0.z * m0.z + m0.w * m0.w
                  + m1.x * m1.x + m1.y * m1.y + m1.z * m1.z + m1.w * m1.w;
#pragma unroll
        for (int o = 32; o > 0; o >>= 1) {
            dot += __shfl_xor(dot, o);
            ss  += __shfl_xor(ss, o);
        }
        float pe = expf(beta * (dot / (sqrtf(ss) + EPS)));
        if (lane == 0) {
            p[row] = pe;
            lsum += pe;
        }
    }
    if (lane == 0) wsum[wid] = lsum;
    __syncthreads();
    if (t == 0) psum[blockIdx.x] = (wsum[0] + wsum[1]) + (wsum[2] + wsum[3]);
}

// ---- mem_new + partial read_new; 2048 blocks x 256, 32 rows/block ----
// each block redundantly reduces psum[0..2047] -> S (deterministic)
__global__ void __launch_bounds__(256) k_update(
        const float* __restrict__ mem, const float* __restrict__ p,
        const float* __restrict__ psum,
        const float* __restrict__ erase, const float* __restrict__ addv,
        float* __restrict__ mem_out, float* __restrict__ partial) {
    __shared__ float red[256];
    __shared__ float4 s_e[128];
    __shared__ float4 s_a[128];
    __shared__ float  s_w[32];
    __shared__ float4 s_red[128];
    int t = threadIdx.x;
    float s = 0.f;
#pragma unroll
    for (int i = 0; i < 8; ++i) s += psum[t + i * 256];
    red[t] = s;
    __syncthreads();
#pragma unroll
    for (int s2 = 128; s2 > 0; s2 >>= 1) {
        if (t < s2) red[t] += red[t + s2];
        __syncthreads();
    }
    float winv = 1.f / red[0];
    if (t < 128) {
        s_e[t] = ((const float4*)erase)[t];
        s_a[t] = ((const float4*)addv)[t];
    }
    int rowBase = blockIdx.x * 32;
    if (t < 32) s_w[t] = p[rowBase + t] * winv;
    __syncthreads();
    int sub = t >> 7;     // 0/1: which of the 2 rows per iteration
    int c4  = t & 127;    // float4 column index
    float4 e4 = s_e[c4];
    float4 a4 = s_a[c4];
    float4 acc = make_float4(0.f, 0.f, 0.f, 0.f);
#pragma unroll 4
    for (int it = 0; it < 16; ++it) {
        int row = rowBase + it * 2 + sub;
        float wr = s_w[it * 2 + sub];
        float4 m4 = ((const float4*)(mem + (size_t)row * M_DIM))[c4];
        float4 n4;
        n4.x = m4.x * (1.f - wr * e4.x) + wr * a4.x;
        n4.y = m4.y * (1.f - wr * e4.y) + wr * a4.y;
        n4.z = m4.z * (1.f - wr * e4.z) + wr * a4.z;
        n4.w = m4.w * (1.f - wr * e4.w) + wr * a4.w;
        ((float4*)(mem_out + (size_t)row * M_DIM))[c4] = n4;
        acc.x += wr * n4.x;
        acc.y += wr * n4.y;
        acc.z += wr * n4.z;
        acc.w += wr * n4.w;
    }
    if (sub) s_red[c4] = acc;
    __syncthreads();
    if (!sub) {
        float4 o = s_red[c4];
        acc.x += o.x; acc.y += o.y; acc.z += o.z; acc.w += o.w;
        ((float4*)(partial + (size_t)blockIdx.x * M_DIM))[c4] = acc;
    }
}

// ---- stage-1 read reduction: 64 blocks x 256; block g sums b in [g*32, g*32+32) ----
__global__ void __launch_bounds__(256) k_red1(const float* __restrict__ partial,
                                              float* __restrict__ out1) {
    int g = blockIdx.x, t = threadIdx.x;
    float s0 = 0.f, s1 = 0.f;
    int b0 = g * 32;
#pragma unroll 4
    for (int b = b0; b < b0 + 32; ++b) {
        s0 += partial[(size_t)b * M_DIM + t];
        s1 += partial[(size_t)b * M_DIM + 256 + t];
    }
    out1[(size_t)g * M_DIM + t] = s0;
    out1[(size_t)g * M_DIM + 256 + t] = s1;
}

// ---- stage-2: 1 block x 512 ----
__global__ void __launch_bounds__(512) k_red2(const float* __restrict__ out1,
                                              float* __restrict__ read_new) {
    int t = threadIdx.x;
    float s = 0.f;
#pragma unroll 4
    for (int g = 0; g < 64; ++g) s += out1[(size_t)g * M_DIM + t];
    read_new[t] = s;
}

extern "C" void kernel_launch(void* const* d_in, const int* in_sizes, int n_in,
                              void* d_out, int out_size, void* d_ws, size_t ws_size,
                              hipStream_t stream) {
    const float* x        = (const float*)d_in[0];
    const float* h0       = (const float*)d_in[1];
    const float* c0       = (const float*)d_in[2];
    const float* memory   = (const float*)d_in[3];
    const float* read_vec = (const float*)d_in[4];
    const float* W_ih     = (const float*)d_in[5];
    const float* b_ih     = (const float*)d_in[6];
    const float* W_hh     = (const float*)d_in[7];
    const float* b_hh     = (const float*)d_in[8];
    const float* W_fc     = (const float*)d_in[9];
    const float* b_fc     = (const float*)d_in[10];
    const float* W_key    = (const float*)d_in[11];
    const float* b_key    = (const float*)d_in[12];
    const float* W_beta   = (const float*)d_in[13];
    const float* b_beta   = (const float*)d_in[14];
    const float* W_erase  = (const float*)d_in[15];
    const float* b_erase  = (const float*)d_in[16];
    const float* W_add    = (const float*)d_in[17];
    const float* b_add    = (const float*)d_in[18];

    float* out      = (float*)d_out;                       // 512
    float* h_out    = out + 512;                           // 1024
    float* c_out    = h_out + 1024;                        // 1024
    float* mem_out  = c_out + 1024;                        // N*M
    float* read_out = mem_out + (size_t)N_ROWS * M_DIM;    // 512

    float* ws     = (float*)d_ws;
    float* kvec   = ws + WS_KVEC;
    float* erase  = ws + WS_ERASE;
    float* addv   = ws + WS_ADD;
    float* scal   = ws + WS_SCAL;
    float* p      = ws + WS_P;
    float* psum   = ws + WS_PSUM;
    float* part   = ws + WS_PART;
    float* out1   = ws + WS_OUT1;

    k_gatecell<<<1024, 256, 0, stream>>>(x, read_vec, h0, c0, W_ih, b_ih, W_hh, b_hh,
                                         h_out, c_out);
    k_heads<<<513, 256, 0, stream>>>(h_out, W_fc, b_fc, W_key, b_key, W_beta, b_beta,
                                     W_erase, b_erase, W_add, b_add,
                                     out, kvec, scal, erase, addv);
    k_simexp<<<NBLK_S, 256, 0, stream>>>(memory, kvec, scal, p, psum);
    k_update<<<NBLK_U, 256, 0, stream>>>(memory, p, psum, erase, addv, mem_out, part);
    k_red1<<<64, 256, 0, stream>>>(part, out1);
    k_red2<<<1, 512, 0, stream>>>(out1, read_out);
}